// Round 2
// baseline (1233.071 us; speedup 1.0000x reference)
//
#include <hip/hip_runtime.h>
#include <hip/hip_bf16.h>

#define NN 20000
#define NE 100000
#define NGR 64

using bf16 = __hip_bfloat16;

__device__ __forceinline__ float bf2f(bf16 v) { return __bfloat162float(v); }

// flag-aware float load: isbf is wave-uniform
__device__ __forceinline__ float ldf(const void* p, int idx, int isbf) {
  if (isbf) return __bfloat162float(((const bf16*)p)[idx]);
  return ((const float*)p)[idx];
}

// ---------------- dtype detector: 1 wave, writes flag (1=bf16, 0=f32) ----
__global__ __launch_bounds__(64) void k_detect(const unsigned short* __restrict__ xr,
                                               int* __restrict__ flag) {
  const int t = threadIdx.x;
  int cnt = 0;
#pragma unroll
  for (int j = 0; j < 4; j++) {
    unsigned short w = xr[t * 4 + j];
    int ex = (w >> 7) & 0xFF;
    cnt += (ex >= 118 && ex <= 131) ? 1 : 0;
  }
#pragma unroll
  for (int m = 32; m >= 1; m >>= 1) cnt += __shfl_xor(cnt, m, 64);
  if (t == 0) *flag = (cnt >= 192) ? 1 : 0;
}

// ---------------- degree histogram ----------------
__global__ __launch_bounds__(256) void k_deg(const int* __restrict__ ei,
                                             int* __restrict__ deg_src,
                                             int* __restrict__ deg_in) {
  int e = blockIdx.x * 256 + threadIdx.x;
  if (e < NE) {
    atomicAdd(&deg_src[ei[e]], 1);
    atomicAdd(&deg_in[ei[NE + e]], 1);
  }
}

// ---------------- single-block exclusive scan, 256 threads x 80 ----------
__global__ __launch_bounds__(256) void k_scan(const int* __restrict__ deg,
                                              int* __restrict__ off,
                                              int* __restrict__ cur) {
  constexpr int T = 256, CH = 80;  // 256*80 = 20480 >= NN
  __shared__ int sums[T];
  const int t = threadIdx.x;
  const int base = t * CH;
  int s = 0;
  for (int j = 0; j < CH; j++) {
    int i = base + j;
    s += (i < NN) ? deg[i] : 0;
  }
  sums[t] = s;
  __syncthreads();
  for (int st = 1; st < T; st <<= 1) {
    int v = (t >= st) ? sums[t - st] : 0;
    __syncthreads();
    sums[t] += v;
    __syncthreads();
  }
  int run = sums[t] - s;  // exclusive prefix of this thread's chunk
  for (int j = 0; j < CH; j++) {
    int i = base + j;
    if (i < NN) {
      int v = deg[i];
      off[i] = run;
      cur[i] = run;
      run += v;
    }
  }
  if (t == T - 1) off[NN] = sums[T - 1];
}

// ---------------- CSR scatter ----------------
__global__ __launch_bounds__(256) void k_scatter(const int* __restrict__ ei,
                                                 int* __restrict__ cur,
                                                 int* __restrict__ ebs) {
  int e = blockIdx.x * 256 + threadIdx.x;
  if (e < NE) {
    int p = atomicAdd(&cur[ei[e]], 1);
    if (p >= 0 && p < NE) ebs[p] = e;
  }
}

// ---------------- edge MLP layer A: z = relu(ea @ eW1 + eb1), bf16 out ----
template <int KH>
__global__ __launch_bounds__(256) void k_zmlp(const void* __restrict__ ea,
                                              const void* __restrict__ eW1,
                                              const void* __restrict__ eb1,
                                              bf16* __restrict__ z,
                                              const int* __restrict__ flag) {
  const int f = *flag;
  const int idx = blockIdx.x * 256 + threadIdx.x;
  const int e = idx / KH;
  const int k = idx - e * KH;
  if (e >= NE) return;
  float a = ldf(eb1, k, f);
#pragma unroll
  for (int i = 0; i < 4; i++) a += ldf(ea, e * 4 + i, f) * ldf(eW1, i * KH + k, f);
  z[idx] = __float2bfloat16(fmaxf(a, 0.f));
}

// ---------------- fused node-first NNConv message pass ----------------
// msg[e][o] = sum_k z[e][k] * Q[src][k][o] + r2[src][o]
// Q[n][k][o] = sum_i h[n][i]*W2[k][i*64+o];  r2[n][o] = sum_i h[n][i]*eb2[i*64+o]
// HMODE: 0 = h is flag-dtype global input, 1 = h is our f32 buffer.
template <int IN, int KH, int HMODE>
__global__ __launch_bounds__(256) void k_fused(
    const void* __restrict__ h_in, const bf16* __restrict__ z,
    const void* __restrict__ W2, const void* __restrict__ eb2,
    const int* __restrict__ ei, const int* __restrict__ src_off,
    const int* __restrict__ ebs, float* __restrict__ agg,
    const int* __restrict__ flag) {
  constexpr int NPG = 16;       // nodes per group (NN/16 = 1250 groups)
  constexpr int KC = 8;         // k per chunk
  constexpr int NCH = KH / KC;  // chunks
  constexpr int EB = 128;       // edge batch
  constexpr int IB = (IN >= 8) ? 8 : IN;

  __shared__ __align__(16) float hA[NPG][IN];
  __shared__ float r2[NPG][64];
  __shared__ __align__(16) float Qc[NPG][KC][64];
  __shared__ __align__(16) unsigned short zB[EB][KC];
  __shared__ int esrc[EB];
  __shared__ int edstS[EB];

  const int f = *flag;
  const int g = blockIdx.x;
  const int tid = threadIdx.x;
  const int o = tid & 63;
  const int kq = tid >> 6;  // wave id 0..3
  const int n0 = g * NPG;

  for (int idx = tid; idx < NPG * IN; idx += 256) {
    int n = idx / IN, i = idx - n * IN;
    float v;
    if (HMODE == 1)
      v = ((const float*)h_in)[(n0 + n) * IN + i];
    else
      v = ldf(h_in, (n0 + n) * IN + i, f);
    hA[n][i] = v;
  }
  __syncthreads();

  {  // r2[n][o]: per-node bias contribution
    const int nb = kq * 4;
    float a0 = 0.f, a1 = 0.f, a2 = 0.f, a3 = 0.f;
    for (int i = 0; i < IN; i++) {
      float wv = ldf(eb2, i * 64 + o, f);
      a0 += hA[nb + 0][i] * wv;
      a1 += hA[nb + 1][i] * wv;
      a2 += hA[nb + 2][i] * wv;
      a3 += hA[nb + 3][i] * wv;
    }
    r2[nb + 0][o] = a0;
    r2[nb + 1][o] = a1;
    r2[nb + 2][o] = a2;
    r2[nb + 3][o] = a3;
  }

  const int estart = src_off[n0];
  const int ecount = src_off[n0 + NPG] - estart;

  for (int b = 0; b < ecount; b += EB) {
    const int bc = min(EB, ecount - b);
    __syncthreads();  // protect meta/r2 from previous batch readers
    int my_eid = -1;
    if (tid < bc) {
      my_eid = ebs[estart + b + tid];
      esrc[tid] = ei[my_eid] - n0;
      edstS[tid] = ei[NE + my_eid];
    }
    float msg[EB / 4];
#pragma unroll
    for (int j = 0; j < EB / 4; j++) msg[j] = 0.f;

    for (int c = 0; c < NCH; c++) {
      // ---- Q chunk: this thread owns (o, k = kq*2 + {0,1}) for 16 nodes
      float acc[NPG * 2];
#pragma unroll
      for (int q = 0; q < NPG * 2; q++) acc[q] = 0.f;
      const int kg0 = c * KC + kq * 2;
      const int w2base = kg0 * (IN * 64) + o;
      for (int ib = 0; ib < IN; ib += IB) {
        float w0[IB], w1[IB];
#pragma unroll
        for (int j = 0; j < IB; j++) {
          w0[j] = ldf(W2, w2base + (ib + j) * 64, f);
          w1[j] = ldf(W2, w2base + IN * 64 + (ib + j) * 64, f);
        }
#pragma unroll
        for (int n = 0; n < NPG; n++) {
          const float* hp = &hA[n][ib];
          float a0 = acc[n * 2 + 0], a1 = acc[n * 2 + 1];
#pragma unroll
          for (int j = 0; j < IB; j++) {
            float hv = hp[j];
            a0 += hv * w0[j];
            a1 += hv * w1[j];
          }
          acc[n * 2 + 0] = a0;
          acc[n * 2 + 1] = a1;
        }
      }
      // z chunk for this batch (own edge, own slot; z is always our bf16)
      if (tid < bc) {
        const uint4 zz =
            *reinterpret_cast<const uint4*>(z + (size_t)my_eid * KH + c * KC);
        *reinterpret_cast<uint4*>(&zB[tid][0]) = zz;
      }
#pragma unroll
      for (int n = 0; n < NPG; n++) {
        Qc[n][kq * 2 + 0][o] = acc[n * 2 + 0];
        Qc[n][kq * 2 + 1][o] = acc[n * 2 + 1];
      }
      __syncthreads();
      // ---- message accumulate: wave kq owns edges e = 4j+kq
#pragma unroll
      for (int j = 0; j < EB / 4; j++) {
        const int e = j * 4 + kq;
        if (e < bc) {
          const int s = esrc[e];
          const uint4 zz = *reinterpret_cast<const uint4*>(&zB[e][0]);
          float m = msg[j];
          m += __uint_as_float(zz.x << 16) * Qc[s][0][o];
          m += __uint_as_float(zz.x & 0xffff0000u) * Qc[s][1][o];
          m += __uint_as_float(zz.y << 16) * Qc[s][2][o];
          m += __uint_as_float(zz.y & 0xffff0000u) * Qc[s][3][o];
          m += __uint_as_float(zz.z << 16) * Qc[s][4][o];
          m += __uint_as_float(zz.z & 0xffff0000u) * Qc[s][5][o];
          m += __uint_as_float(zz.w << 16) * Qc[s][6][o];
          m += __uint_as_float(zz.w & 0xffff0000u) * Qc[s][7][o];
          msg[j] = m;
        }
      }
      __syncthreads();
    }
    // ---- flush batch
#pragma unroll
    for (int j = 0; j < EB / 4; j++) {
      const int e = j * 4 + kq;
      if (e < bc) {
        float v = msg[j] + r2[esrc[e]][o];
        atomicAdd(&agg[(size_t)edstS[e] * 64 + o], v);
      }
    }
  }
}

// ---------------- wave-wide sum over 64 lanes ----------------
__device__ __forceinline__ float wave_sum(float v) {
#pragma unroll
  for (int m = 32; m >= 1; m >>= 1) v += __shfl_xor(v, m, 64);
  return v;
}

// ---------------- node update 1: h1 = LN(relu(agg/deg + x@root1 + bias1)) -
__global__ __launch_bounds__(256) void k_node1(
    const float* __restrict__ agg1, const int* __restrict__ deg_in,
    const void* __restrict__ x, const void* __restrict__ root1,
    const void* __restrict__ bias1, const void* __restrict__ g1,
    const void* __restrict__ b1, float* __restrict__ h1,
    const int* __restrict__ flag) {
  const int f = *flag;
  const int n = blockIdx.x * 4 + (threadIdx.x >> 6);
  const int o = threadIdx.x & 63;
  float v = agg1[n * 64 + o] / fmaxf((float)deg_in[n], 1.f);
#pragma unroll
  for (int i = 0; i < 4; i++) v += ldf(x, n * 4 + i, f) * ldf(root1, i * 64 + o, f);
  v += ldf(bias1, o, f);
  v = fmaxf(v, 0.f);
  const float mu = wave_sum(v) * (1.f / 64.f);
  const float d = v - mu;
  const float var = wave_sum(d * d) * (1.f / 64.f);
  h1[n * 64 + o] = d * rsqrtf(var + 1e-5f) * ldf(g1, o, f) + ldf(b1, o, f);
}

// ---------------- node update 2 + pooled accumulation ----------------
__global__ __launch_bounds__(256) void k_node2(
    const float* __restrict__ agg2, const int* __restrict__ deg_in,
    const float* __restrict__ h1, const void* __restrict__ root2,
    const void* __restrict__ bias2, const void* __restrict__ g2,
    const void* __restrict__ b2, const int* __restrict__ batch,
    float* __restrict__ psum, float* __restrict__ pcnt,
    const int* __restrict__ flag) {
  const int f = *flag;
  const int n = blockIdx.x * 4 + (threadIdx.x >> 6);
  const int o = threadIdx.x & 63;
  float v = agg2[n * 64 + o] / fmaxf((float)deg_in[n], 1.f);
  const float* hrow = h1 + (size_t)n * 64;
  for (int i = 0; i < 64; i++) v += hrow[i] * ldf(root2, i * 64 + o, f);
  v += ldf(bias2, o, f);
  v = fmaxf(v, 0.f);
  const float mu = wave_sum(v) * (1.f / 64.f);
  const float d = v - mu;
  const float var = wave_sum(d * d) * (1.f / 64.f);
  const float out = d * rsqrtf(var + 1e-5f) * ldf(g2, o, f) + ldf(b2, o, f);
  const int bi = batch[n];
  atomicAdd(&psum[bi * 64 + o], out);
  if (o == 0) atomicAdd(&pcnt[bi], 1.f);
}

// ---------------- final mean + dtype-flagged output ----------------
__global__ __launch_bounds__(256) void k_out(const float* __restrict__ psum,
                                             const float* __restrict__ pcnt,
                                             void* __restrict__ out,
                                             const int* __restrict__ flag) {
  const int idx = blockIdx.x * 256 + threadIdx.x;  // 4096 total
  float v = psum[idx] / fmaxf(pcnt[idx >> 6], 1.f);
  if (*flag)
    ((bf16*)out)[idx] = __float2bfloat16(v);
  else
    ((float*)out)[idx] = v;
}

extern "C" void kernel_launch(void* const* d_in, const int* in_sizes, int n_in,
                              void* d_out, int out_size, void* d_ws,
                              size_t ws_size, hipStream_t stream) {
  (void)in_sizes; (void)n_in; (void)out_size; (void)ws_size;
  const void* x = d_in[0];
  const int* ei = (const int*)d_in[1];
  const void* ea = d_in[2];
  const int* batch = (const int*)d_in[3];
  const void* eW1_1 = d_in[4];
  const void* eb1_1 = d_in[5];
  const void* eW2_1 = d_in[6];
  const void* eb2_1 = d_in[7];
  const void* root1 = d_in[8];
  const void* bias1 = d_in[9];
  const void* g1 = d_in[10];
  const void* b1 = d_in[11];
  const void* eW1_2 = d_in[12];
  const void* eb1_2 = d_in[13];
  const void* eW2_2 = d_in[14];
  const void* eb2_2 = d_in[15];
  const void* root2 = d_in[16];
  const void* bias2 = d_in[17];
  const void* g2 = d_in[18];
  const void* b2 = d_in[19];

  char* w = (char*)d_ws;
  size_t off = 0;
  auto alloc = [&](size_t bytes) -> void* {
    void* p = w + off;
    off = (off + bytes + 255) & ~(size_t)255;
    return p;
  };
  float* agg1 = (float*)alloc((size_t)NN * 64 * 4);
  float* agg2 = (float*)alloc((size_t)NN * 64 * 4);
  float* psum = (float*)alloc((size_t)NGR * 64 * 4);
  float* pcnt = (float*)alloc((size_t)NGR * 4);
  int* deg_src = (int*)alloc((size_t)NN * 4);
  int* deg_in = (int*)alloc((size_t)NN * 4);
  int* src_off = (int*)alloc((size_t)(NN + 1) * 4);
  int* cur = (int*)alloc((size_t)NN * 4);
  int* ebs = (int*)alloc((size_t)NE * 4);
  int* flag = (int*)alloc(256);
  float* h1 = (float*)alloc((size_t)NN * 64 * 4);
  bf16* z1 = (bf16*)alloc((size_t)NE * 64 * 2);
  bf16* z2 = (bf16*)alloc((size_t)NE * 128 * 2);
  const size_t zero_bytes = off;  // zero EVERYTHING we use (~54.5 MB)

  hipMemsetAsync(d_ws, 0, zero_bytes, stream);

  k_detect<<<1, 64, 0, stream>>>((const unsigned short*)x, flag);
  k_deg<<<(NE + 255) / 256, 256, 0, stream>>>(ei, deg_src, deg_in);
  k_scan<<<1, 256, 0, stream>>>(deg_src, src_off, cur);
  k_scatter<<<(NE + 255) / 256, 256, 0, stream>>>(ei, cur, ebs);
  k_zmlp<64><<<(NE * 64) / 256, 256, 0, stream>>>(ea, eW1_1, eb1_1, z1, flag);
  k_fused<4, 64, 0><<<NN / 16, 256, 0, stream>>>(x, z1, eW2_1, eb2_1, ei,
                                                 src_off, ebs, agg1, flag);
  k_node1<<<NN / 4, 256, 0, stream>>>(agg1, deg_in, x, root1, bias1, g1, b1,
                                      h1, flag);
  k_zmlp<128><<<(NE * 128) / 256, 256, 0, stream>>>(ea, eW1_2, eb1_2, z2, flag);
  k_fused<64, 128, 1><<<NN / 16, 256, 0, stream>>>(h1, z2, eW2_2, eb2_2, ei,
                                                   src_off, ebs, agg2, flag);
  k_node2<<<NN / 4, 256, 0, stream>>>(agg2, deg_in, h1, root2, bias2, g2, b2,
                                      batch, psum, pcnt, flag);
  k_out<<<(NGR * 64) / 256, 256, 0, stream>>>(psum, pcnt, d_out, flag);
}

// Round 3
// 633.987 us; speedup vs baseline: 1.9449x; 1.9449x over previous
//
#include <hip/hip_runtime.h>
#include <hip/hip_bf16.h>

#define NN 20000
#define NE 100000
#define NGR 64

using bf16 = __hip_bfloat16;
typedef __attribute__((ext_vector_type(8))) short v8s;
typedef __attribute__((ext_vector_type(4))) float v4f;

__device__ __forceinline__ float ldf(const void* p, int idx, int isbf) {
  if (isbf) return __bfloat162float(((const bf16*)p)[idx]);
  return ((const float*)p)[idx];
}
__device__ __forceinline__ unsigned short f2bfbits(float v) {
  unsigned int b = __float_as_uint(v);
  b += 0x7fffu + ((b >> 16) & 1u);
  return (unsigned short)(b >> 16);
}

// ---------------- dtype detector: 1 wave, writes flag (1=bf16, 0=f32) ----
__global__ __launch_bounds__(64) void k_detect(const unsigned short* __restrict__ xr,
                                               int* __restrict__ flag) {
  const int t = threadIdx.x;
  int cnt = 0;
#pragma unroll
  for (int j = 0; j < 4; j++) {
    unsigned short w = xr[t * 4 + j];
    int ex = (w >> 7) & 0xFF;
    cnt += (ex >= 118 && ex <= 131) ? 1 : 0;
  }
#pragma unroll
  for (int m = 32; m >= 1; m >>= 1) cnt += __shfl_xor(cnt, m, 64);
  if (t == 0) *flag = (cnt >= 192) ? 1 : 0;
}

// ---------------- degree histogram ----------------
__global__ __launch_bounds__(256) void k_deg(const int* __restrict__ ei,
                                             int* __restrict__ deg_src,
                                             int* __restrict__ deg_in) {
  int e = blockIdx.x * 256 + threadIdx.x;
  if (e < NE) {
    atomicAdd(&deg_src[ei[e]], 1);
    atomicAdd(&deg_in[ei[NE + e]], 1);
  }
}

// ---------------- single-block exclusive scan, 256 threads x 80 ----------
__global__ __launch_bounds__(256) void k_scan(const int* __restrict__ deg,
                                              int* __restrict__ off,
                                              int* __restrict__ cur) {
  constexpr int T = 256, CH = 80;  // 256*80 = 20480 >= NN
  __shared__ int sums[T];
  const int t = threadIdx.x;
  const int base = t * CH;
  int s = 0;
  for (int j = 0; j < CH; j++) {
    int i = base + j;
    s += (i < NN) ? deg[i] : 0;
  }
  sums[t] = s;
  __syncthreads();
  for (int st = 1; st < T; st <<= 1) {
    int v = (t >= st) ? sums[t - st] : 0;
    __syncthreads();
    sums[t] += v;
    __syncthreads();
  }
  int run = sums[t] - s;
  for (int j = 0; j < CH; j++) {
    int i = base + j;
    if (i < NN) {
      int v = deg[i];
      off[i] = run;
      cur[i] = run;
      run += v;
    }
  }
  if (t == T - 1) off[NN] = sums[T - 1];
}

// ---------------- CSR scatter ----------------
__global__ __launch_bounds__(256) void k_scatter(const int* __restrict__ ei,
                                                 int* __restrict__ cur,
                                                 int* __restrict__ ebs) {
  int e = blockIdx.x * 256 + threadIdx.x;
  if (e < NE) {
    int p = atomicAdd(&cur[ei[e]], 1);
    if (p >= 0 && p < NE) ebs[p] = e;
  }
}

// ---------------- W2 -> MFMA B-fragment pre-shuffle (IN must be 64) -------
// W2s[F*512 + lane*8 + j] = W2[k2][i*64 + o2],
//   F=(k2*4+ot)*2+ks, i=ks*32+(lane>>4)*8+j, o2=ot*16+(lane&15)
template <int KH, int IN>
__global__ __launch_bounds__(256) void k_shuffle(const void* __restrict__ W2,
                                                 unsigned short* __restrict__ W2s,
                                                 const int* __restrict__ flag) {
  const int f = *flag;
  int t = blockIdx.x * 256 + threadIdx.x;  // KH*8*64 threads total
  int lane = t & 63, F = t >> 6;
  int ks = F & 1, ot = (F >> 1) & 3, k2 = F >> 3;
  int quad = lane >> 4, col = lane & 15;
  unsigned short tmp[8];
#pragma unroll
  for (int j = 0; j < 8; j++) {
    int i = ks * 32 + quad * 8 + j;
    tmp[j] = f2bfbits(ldf(W2, k2 * (IN * 64) + i * 64 + ot * 16 + col, f));
  }
  *(uint4*)(W2s + (size_t)F * 512 + lane * 8) = *(uint4*)tmp;
}

// ---------------- fused node-first NNConv message pass ----------------
// msg[e][o] = sum_k z[e][k]*Q[src[e]][k][o] + r2[src[e]][o]
//   z[e][k] = relu(ea[e]@eW1 + eb1)[k]   (computed inline per chunk)
//   Q[n][k][o] = sum_i h[n][i]*W2[k][i*64+o]   (MFMA if QMFMA, else VALU)
//   r2[n][o] = sum_i h[n][i]*eb2[i*64+o]
template <int IN, int KH, int HMODE, int QMFMA>
__global__ __launch_bounds__(256, 3) void k_fused2(
    const void* __restrict__ h_in, const void* __restrict__ eW1,
    const void* __restrict__ eb1, const void* __restrict__ W2,
    const unsigned short* __restrict__ W2s, const void* __restrict__ eb2,
    const void* __restrict__ ea, const int* __restrict__ ei,
    const int* __restrict__ src_off, const int* __restrict__ ebs,
    float* __restrict__ agg, const int* __restrict__ flag) {
  constexpr int NPG = 16, KC = 8, NCH = KH / KC, EB = 128;
  constexpr int QST = KC * 64 + 1;  // 513: quad-spread on MFMA C-writes

  __shared__ float hA[NPG][IN];
  __shared__ float r2[NPG][64];
  __shared__ float Qc[NPG * QST];
  __shared__ float eW1S[4][KH];
  __shared__ float ebS[KH];
  __shared__ float eaS[EB][4];
  __shared__ __align__(16) unsigned short zB[EB][KC];
  __shared__ int esrcS[EB], edstS[EB];
  __shared__ __align__(16) unsigned short hF[QMFMA ? 2 : 1][64][8];

  const int f = *flag;
  const int tid = threadIdx.x;
  const int o = tid & 63;
  const int kq = tid >> 6;  // wave id 0..3
  const int n0 = blockIdx.x * NPG;

  // ---- stage h rows, eW1, eb1 ----
  for (int idx = tid; idx < NPG * IN; idx += 256) {
    int n = idx / IN, i = idx - n * IN;
    hA[n][i] = (HMODE == 1) ? ((const float*)h_in)[(n0 + n) * IN + i]
                            : ldf(h_in, (n0 + n) * IN + i, f);
  }
  for (int idx = tid; idx < 4 * KH; idx += 256)
    ((float*)eW1S)[idx] = ldf(eW1, idx, f);
  for (int idx = tid; idx < KH; idx += 256) ebS[idx] = ldf(eb1, idx, f);
  __syncthreads();

  {  // r2[n][o] (wave kq owns nodes kq*4..kq*4+3)
    const int nb = kq * 4;
    float a0 = 0.f, a1 = 0.f, a2 = 0.f, a3 = 0.f;
    for (int i = 0; i < IN; i++) {
      float wv = ldf(eb2, i * 64 + o, f);
      a0 += hA[nb + 0][i] * wv;
      a1 += hA[nb + 1][i] * wv;
      a2 += hA[nb + 2][i] * wv;
      a3 += hA[nb + 3][i] * wv;
    }
    r2[nb + 0][o] = a0;
    r2[nb + 1][o] = a1;
    r2[nb + 2][o] = a2;
    r2[nb + 3][o] = a3;
  }
  if constexpr (QMFMA) {  // A-fragment staging (lane l: m=l&15, k=quad*8+j)
    if (tid < 128) {
      int l = tid & 63, ks = tid >> 6;
#pragma unroll
      for (int j = 0; j < 8; j++)
        hF[ks][l][j] = f2bfbits(hA[l & 15][ks * 32 + (l >> 4) * 8 + j]);
    }
  }
  __syncthreads();

  v8s aF0 = {}, aF1 = {};
  if constexpr (QMFMA) {
    aF0 = *(const v8s*)&hF[0][o][0];
    aF1 = *(const v8s*)&hF[1][o][0];
  }

  const int estart = src_off[n0];
  const int ecount = src_off[n0 + NPG] - estart;

  for (int b = 0; b < ecount; b += EB) {
    const int bc = min(EB, ecount - b);
    __syncthreads();  // prev-batch message reads done before meta overwrite
    if (tid < bc) {
      int eid = ebs[estart + b + tid];
      esrcS[tid] = ei[eid] - n0;
      edstS[tid] = ei[NE + eid];
#pragma unroll
      for (int i = 0; i < 4; i++) eaS[tid][i] = ldf(ea, eid * 4 + i, f);
    }
    __syncthreads();  // meta/eaS visible to all

    float msg[EB / 4];
#pragma unroll
    for (int j = 0; j < EB / 4; j++) msg[j] = 0.f;
    const int lo = (bc * kq) >> 2, hi = (bc * (kq + 1)) >> 2;

    for (int c = 0; c < NCH; c++) {
      // ---- step 1: compute Q-chunk into regs + z-chunk into regs ----
      v4f acc8[8];
      float accv[NPG * 2];
      if constexpr (QMFMA) {
#pragma unroll
        for (int nt = 0; nt < 8; nt++) {
          acc8[nt] = (v4f){0.f, 0.f, 0.f, 0.f};
          const int k2 = c * KC + kq * 2 + (nt >> 2);
          const int Fb = (k2 * 4 + (nt & 3)) * 2;
          v8s b0 = *(const v8s*)(W2s + (size_t)Fb * 512 + o * 8);
          v8s b1 = *(const v8s*)(W2s + (size_t)(Fb + 1) * 512 + o * 8);
          acc8[nt] =
              __builtin_amdgcn_mfma_f32_16x16x32_bf16(aF0, b0, acc8[nt], 0, 0, 0);
          acc8[nt] =
              __builtin_amdgcn_mfma_f32_16x16x32_bf16(aF1, b1, acc8[nt], 0, 0, 0);
        }
      } else {
        const int kg0 = c * KC + kq * 2;
        const int w2base = kg0 * (IN * 64) + o;
        float w0[IN], w1[IN];
#pragma unroll
        for (int j = 0; j < IN; j++) {
          w0[j] = ldf(W2, w2base + j * 64, f);
          w1[j] = ldf(W2, w2base + IN * 64 + j * 64, f);
        }
#pragma unroll
        for (int n = 0; n < NPG; n++) {
          float a0 = 0.f, a1 = 0.f;
#pragma unroll
          for (int j = 0; j < IN; j++) {
            float hv = hA[n][j];
            a0 += hv * w0[j];
            a1 += hv * w1[j];
          }
          accv[n * 2 + 0] = a0;
          accv[n * 2 + 1] = a1;
        }
      }
      // z for this chunk: thread -> (edge = tid&127, 4 k's per half)
      const int ze = tid & 127, khalf = tid >> 7;
      float zv[4];
      if (ze < bc) {
#pragma unroll
        for (int jj = 0; jj < 4; jj++) {
          int k2 = c * KC + khalf * 4 + jj;
          float a = ebS[k2];
#pragma unroll
          for (int i = 0; i < 4; i++) a += eaS[ze][i] * eW1S[i][k2];
          zv[jj] = fmaxf(a, 0.f);
        }
      }
      __syncthreads();  // prev message stage done reading Qc/zB
      // ---- step 3: write Qc + zB ----
      if constexpr (QMFMA) {
        const int quad = o >> 4;
#pragma unroll
        for (int nt = 0; nt < 8; nt++) {
          const int kc2 = kq * 2 + (nt >> 2);
          const int o2 = (nt & 3) * 16 + (o & 15);
#pragma unroll
          for (int r = 0; r < 4; r++)
            Qc[(quad * 4 + r) * QST + kc2 * 64 + o2] = acc8[nt][r];
        }
      } else {
#pragma unroll
        for (int n = 0; n < NPG; n++) {
          Qc[n * QST + (kq * 2 + 0) * 64 + o] = accv[n * 2 + 0];
          Qc[n * QST + (kq * 2 + 1) * 64 + o] = accv[n * 2 + 1];
        }
      }
      if (ze < bc) {
        unsigned short zb[4];
#pragma unroll
        for (int jj = 0; jj < 4; jj++) zb[jj] = f2bfbits(zv[jj]);
        *(uint2*)&zB[ze][khalf * 4] = *(uint2*)zb;
      }
      __syncthreads();
      // ---- step 5: message accumulate (contiguous edges, src-cached Q) ----
      float q0 = 0, q1 = 0, q2 = 0, q3 = 0, q4 = 0, q5 = 0, q6 = 0, q7 = 0;
      int sprev = -1;
#pragma unroll
      for (int j = 0; j < EB / 4; j++) {
        const int e = lo + j;
        if (e < hi) {
          const int s = esrcS[e];  // wave-uniform broadcast
          if (s != sprev) {
            const float* qp = &Qc[s * QST + o];
            q0 = qp[0 * 64]; q1 = qp[1 * 64]; q2 = qp[2 * 64]; q3 = qp[3 * 64];
            q4 = qp[4 * 64]; q5 = qp[5 * 64]; q6 = qp[6 * 64]; q7 = qp[7 * 64];
            sprev = s;
          }
          const uint4 zz = *(const uint4*)&zB[e][0];
          float m = msg[j];
          m += __uint_as_float(zz.x << 16) * q0;
          m += __uint_as_float(zz.x & 0xffff0000u) * q1;
          m += __uint_as_float(zz.y << 16) * q2;
          m += __uint_as_float(zz.y & 0xffff0000u) * q3;
          m += __uint_as_float(zz.z << 16) * q4;
          m += __uint_as_float(zz.z & 0xffff0000u) * q5;
          m += __uint_as_float(zz.w << 16) * q6;
          m += __uint_as_float(zz.w & 0xffff0000u) * q7;
          msg[j] = m;
        }
      }
    }  // chunks
    // ---- flush batch ----
#pragma unroll
    for (int j = 0; j < EB / 4; j++) {
      const int e = lo + j;
      if (e < hi)
        atomicAdd(&agg[(size_t)edstS[e] * 64 + o], msg[j] + r2[esrcS[e]][o]);
    }
  }  // batches
}

// ---------------- wave-wide sum over 64 lanes ----------------
__device__ __forceinline__ float wave_sum(float v) {
#pragma unroll
  for (int m = 32; m >= 1; m >>= 1) v += __shfl_xor(v, m, 64);
  return v;
}

// ---------------- node update 1: h1 = LN(relu(agg/deg + x@root1 + bias1)) -
__global__ __launch_bounds__(256) void k_node1(
    const float* __restrict__ agg1, const int* __restrict__ deg_in,
    const void* __restrict__ x, const void* __restrict__ root1,
    const void* __restrict__ bias1, const void* __restrict__ g1,
    const void* __restrict__ b1, float* __restrict__ h1,
    const int* __restrict__ flag) {
  const int f = *flag;
  const int n = blockIdx.x * 4 + (threadIdx.x >> 6);
  const int o = threadIdx.x & 63;
  float v = agg1[n * 64 + o] / fmaxf((float)deg_in[n], 1.f);
#pragma unroll
  for (int i = 0; i < 4; i++) v += ldf(x, n * 4 + i, f) * ldf(root1, i * 64 + o, f);
  v += ldf(bias1, o, f);
  v = fmaxf(v, 0.f);
  const float mu = wave_sum(v) * (1.f / 64.f);
  const float d = v - mu;
  const float var = wave_sum(d * d) * (1.f / 64.f);
  h1[n * 64 + o] = d * rsqrtf(var + 1e-5f) * ldf(g1, o, f) + ldf(b1, o, f);
}

// ---------------- node update 2 + pooled accumulation ----------------
__global__ __launch_bounds__(256) void k_node2(
    const float* __restrict__ agg2, const int* __restrict__ deg_in,
    const float* __restrict__ h1, const void* __restrict__ root2,
    const void* __restrict__ bias2, const void* __restrict__ g2,
    const void* __restrict__ b2, const int* __restrict__ batch,
    float* __restrict__ psum, float* __restrict__ pcnt,
    const int* __restrict__ flag) {
  const int f = *flag;
  const int n = blockIdx.x * 4 + (threadIdx.x >> 6);
  const int o = threadIdx.x & 63;
  float v = agg2[n * 64 + o] / fmaxf((float)deg_in[n], 1.f);
  const float* hrow = h1 + (size_t)n * 64;
  for (int i = 0; i < 64; i++) v += hrow[i] * ldf(root2, i * 64 + o, f);
  v += ldf(bias2, o, f);
  v = fmaxf(v, 0.f);
  const float mu = wave_sum(v) * (1.f / 64.f);
  const float d = v - mu;
  const float var = wave_sum(d * d) * (1.f / 64.f);
  const float out = d * rsqrtf(var + 1e-5f) * ldf(g2, o, f) + ldf(b2, o, f);
  const int bi = batch[n];
  atomicAdd(&psum[bi * 64 + o], out);
  if (o == 0) atomicAdd(&pcnt[bi], 1.f);
}

// ---------------- final mean + dtype-flagged output ----------------
__global__ __launch_bounds__(256) void k_out(const float* __restrict__ psum,
                                             const float* __restrict__ pcnt,
                                             void* __restrict__ out,
                                             const int* __restrict__ flag) {
  const int idx = blockIdx.x * 256 + threadIdx.x;  // 4096 total
  float v = psum[idx] / fmaxf(pcnt[idx >> 6], 1.f);
  if (*flag)
    ((bf16*)out)[idx] = __float2bfloat16(v);
  else
    ((float*)out)[idx] = v;
}

extern "C" void kernel_launch(void* const* d_in, const int* in_sizes, int n_in,
                              void* d_out, int out_size, void* d_ws,
                              size_t ws_size, hipStream_t stream) {
  (void)in_sizes; (void)n_in; (void)out_size; (void)ws_size;
  const void* x = d_in[0];
  const int* ei = (const int*)d_in[1];
  const void* ea = d_in[2];
  const int* batch = (const int*)d_in[3];
  const void* eW1_1 = d_in[4];
  const void* eb1_1 = d_in[5];
  const void* eW2_1 = d_in[6];
  const void* eb2_1 = d_in[7];
  const void* root1 = d_in[8];
  const void* bias1 = d_in[9];
  const void* g1 = d_in[10];
  const void* b1 = d_in[11];
  const void* eW1_2 = d_in[12];
  const void* eb1_2 = d_in[13];
  const void* eW2_2 = d_in[14];
  const void* eb2_2 = d_in[15];
  const void* root2 = d_in[16];
  const void* bias2 = d_in[17];
  const void* g2 = d_in[18];
  const void* b2 = d_in[19];

  char* w = (char*)d_ws;
  size_t off = 0;
  auto alloc = [&](size_t bytes) -> void* {
    void* p = w + off;
    off = (off + bytes + 255) & ~(size_t)255;
    return p;
  };
  float* agg1 = (float*)alloc((size_t)NN * 64 * 4);
  float* agg2 = (float*)alloc((size_t)NN * 64 * 4);
  float* psum = (float*)alloc((size_t)NGR * 64 * 4);
  float* pcnt = (float*)alloc((size_t)NGR * 4);
  int* deg_src = (int*)alloc((size_t)NN * 4);
  int* deg_in = (int*)alloc((size_t)NN * 4);
  const size_t zero_bytes = off;  // everything above must start at 0
  int* src_off = (int*)alloc((size_t)(NN + 1) * 4);
  int* cur = (int*)alloc((size_t)NN * 4);
  int* ebs = (int*)alloc((size_t)NE * 4);
  int* flag = (int*)alloc(256);
  float* h1 = (float*)alloc((size_t)NN * 64 * 4);
  unsigned short* W2s = (unsigned short*)alloc((size_t)128 * 8 * 64 * 8 * 2);

  hipMemsetAsync(d_ws, 0, zero_bytes, stream);

  k_detect<<<1, 64, 0, stream>>>((const unsigned short*)x, flag);
  k_deg<<<(NE + 255) / 256, 256, 0, stream>>>(ei, deg_src, deg_in);
  k_scan<<<1, 256, 0, stream>>>(deg_src, src_off, cur);
  k_scatter<<<(NE + 255) / 256, 256, 0, stream>>>(ei, cur, ebs);
  k_shuffle<128, 64><<<256, 256, 0, stream>>>(eW2_2, W2s, flag);
  k_fused2<4, 64, 0, 0><<<NN / 16, 256, 0, stream>>>(
      x, eW1_1, eb1_1, eW2_1, W2s, eb2_1, ea, ei, src_off, ebs, agg1, flag);
  k_node1<<<NN / 4, 256, 0, stream>>>(agg1, deg_in, x, root1, bias1, g1, b1,
                                      h1, flag);
  k_fused2<64, 128, 1, 1><<<NN / 16, 256, 0, stream>>>(
      h1, eW1_2, eb1_2, eW2_2, W2s, eb2_2, ea, ei, src_off, ebs, agg2, flag);
  k_node2<<<NN / 4, 256, 0, stream>>>(agg2, deg_in, h1, root2, bias2, g2, b2,
                                      batch, psum, pcnt, flag);
  k_out<<<(NGR * 64) / 256, 256, 0, stream>>>(psum, pcnt, d_out, flag);
}